// Round 2
// baseline (684.250 us; speedup 1.0000x reference)
//
#include <hip/hip_runtime.h>
#include <math.h>

// PQ train-mode forward, MI355X fp32 VALU kernel.
// z: [8,4096,512] fp32 -> points N=32768, S=8 subspaces, D=64
// weight: [S=8][K=256][D=64] fp32
// out: z_q (16777216 fp32) ++ loss (1 fp32)

#define SNS   8
#define KCW   256
#define DCW   64
#define NPTS  32768
#define SD    512
#define PT    128          // points per block
#define EPSF  1e-5f
#define EPS2F 1e-10f

#define W_STRIDE 68        // floats; 272B rows -> 16B aligned, even bank spread
#define Z_STRIDE 68
#define R_STRIDE 260       // floats; 1040B rows -> 16B aligned, conflict-free multicast

#define W_OFF   0
#define W_FL    (KCW * W_STRIDE)          // 17408
#define Z_OFF   (W_OFF + W_FL)            // 17408
#define Z_FL    (PT * Z_STRIDE)           // 8704
#define R_OFF   (Z_OFF + Z_FL)            // 26112
#define R_FL    (4 * 8 * R_STRIDE)        // 8320
#define C2_OFF  (R_OFF + R_FL)            // 34432
#define X2_OFF  (C2_OFF + KCW)            // 34688
#define RED_OFF (X2_OFF + PT)             // 34816
#define LDS_FL  (RED_OFF + 8)             // 34824
#define LDS_BYTES (LDS_FL * 4)            // 139296 B < 160 KiB

__global__ void pq_zero_loss(float* loss) { *loss = 0.0f; }

__global__ __launch_bounds__(256, 1)
void pq_main(const float* __restrict__ z, const float* __restrict__ w,
             float* __restrict__ out, float* __restrict__ loss_out) {
  extern __shared__ float lds[];
  float* w68 = lds + W_OFF;
  float* zl  = lds + Z_OFF;
  float* rt  = lds + R_OFF;
  float* c2l = lds + C2_OFF;
  float* x2l = lds + X2_OFF;
  float* red = lds + RED_OFF;

  const int t    = threadIdx.x;
  const int s    = blockIdx.x & 7;       // s = bx%8: XCD-friendly weight reuse
  const int tile = blockIdx.x >> 3;
  const int n0   = tile * PT;

  // ---- stage weight[s] -> w68 [K][68] (coalesced float4) ----
  {
    const float* ws = w + (size_t)s * (KCW * DCW);
    #pragma unroll
    for (int pass = 0; pass < 16; ++pass) {
      int idx = pass * 256 + t;          // float4 index in [0,4096)
      int k  = idx >> 4;
      int d4 = idx & 15;
      float4 v = *(const float4*)(ws + idx * 4);
      *(float4*)(w68 + k * W_STRIDE + d4 * 4) = v;
    }
  }
  // ---- stage z tile -> zl [PT][68]; x2 per point via 16-lane shuffle ----
  {
    #pragma unroll
    for (int pass = 0; pass < 8; ++pass) {
      int i  = pass * 16 + (t >> 4);
      int d4 = t & 15;
      float4 v = *(const float4*)(z + (size_t)(n0 + i) * SD + s * DCW + d4 * 4);
      *(float4*)(zl + i * Z_STRIDE + d4 * 4) = v;
      float sq = v.x*v.x + v.y*v.y + v.z*v.z + v.w*v.w;
      sq += __shfl_xor(sq, 1);
      sq += __shfl_xor(sq, 2);
      sq += __shfl_xor(sq, 4);
      sq += __shfl_xor(sq, 8);
      if (d4 == 0) x2l[i] = sq;
    }
  }
  __syncthreads();
  // ---- c2[k] = ||w_k||^2 ----
  {
    float acc = 0.f;
    const float* row = w68 + t * W_STRIDE;
    #pragma unroll
    for (int d4 = 0; d4 < 16; ++d4) {
      float4 v = *(const float4*)(row + d4 * 4);
      acc += v.x*v.x + v.y*v.y + v.z*v.z + v.w*v.w;
    }
    c2l[t] = acc;
  }
  __syncthreads();

  const int wave = t >> 6;
  const int l    = t & 63;
  float* rtw = rt + wave * (8 * R_STRIDE);

  float c2r[4];
  #pragma unroll
  for (int g = 0; g < 4; ++g) c2r[g] = c2l[l + 64 * g];

  float lq_acc = 0.f, lw_acc = 0.f;
  const int psub = l & 3;
  const int d4b  = l >> 2;

  for (int gi = 0; gi < 4; ++gi) {
    const int p0 = wave * 32 + gi * 8;

    // ================= Phase A: xc[p][k]  (k = l + 64g) =================
    float acc[8][4];
    #pragma unroll
    for (int p = 0; p < 8; ++p)
      #pragma unroll
      for (int g = 0; g < 4; ++g) acc[p][g] = 0.f;

    const float* wbase = w68 + l * W_STRIDE;
    #pragma unroll 4
    for (int d4 = 0; d4 < 16; ++d4) {
      float4 wv[4];
      #pragma unroll
      for (int g = 0; g < 4; ++g)
        wv[g] = *(const float4*)(wbase + g * (64 * W_STRIDE) + d4 * 4);
      #pragma unroll
      for (int p = 0; p < 8; ++p) {
        const float4 zv = *(const float4*)(zl + (p0 + p) * Z_STRIDE + d4 * 4);
        #pragma unroll
        for (int g = 0; g < 4; ++g) {
          acc[p][g] = fmaf(zv.x, wv[g].x, acc[p][g]);
          acc[p][g] = fmaf(zv.y, wv[g].y, acc[p][g]);
          acc[p][g] = fmaf(zv.z, wv[g].z, acc[p][g]);
          acc[p][g] = fmaf(zv.w, wv[g].w, acc[p][g]);
        }
      }
    }

    // ======== Phase A epilogue: d2, r, argmin, R, z_q write, loss_q ========
    float Rme0 = 1.f, Rme1 = 1.f;     // per-lane: R for points psub, psub+4
    int   kq0  = 0,   kq1  = 0;       // per-lane: kmin for points psub, psub+4
    #pragma unroll
    for (int p = 0; p < 8; ++p) {
      const float x2 = x2l[p0 + p];
      float d2g[4];
      #pragma unroll
      for (int g = 0; g < 4; ++g) {
        float m = fmaf(-2.f, acc[p][g], x2 + c2r[g]);
        d2g[g] = fmaxf(m, 0.f);
      }
      float dmin = d2g[0];
      int   kmin = l;
      float rsum = 0.f;
      #pragma unroll
      for (int g = 0; g < 4; ++g) {
        float r = rsqrtf(fmaxf(d2g[g], EPS2F));   // 1/max(dist,EPS)
        rsum += r;
        rtw[p * R_STRIDE + l + 64 * g] = r;
        if (g > 0 && d2g[g] < dmin) { dmin = d2g[g]; kmin = l + 64 * g; }
      }
      // 64-lane butterfly argmin (tie -> smaller k, matches jnp.argmin)
      #pragma unroll
      for (int off = 1; off < 64; off <<= 1) {
        float od = __shfl_xor(dmin, off);
        int   ok = __shfl_xor(kmin, off);
        if (od < dmin || (od == dmin && ok < kmin)) { dmin = od; kmin = ok; }
      }
      #pragma unroll
      for (int off = 1; off < 64; off <<= 1) rsum += __shfl_xor(rsum, off);

      if ((p & 3) == psub) {
        if (p < 4) { Rme0 = rsum; kq0 = kmin; }
        else       { Rme1 = rsum; kq1 = kmin; }
      }
      // write z_q (coalesced 256B/point) + loss_q = sum_d (z-w_q)^2
      const float wq = w68[kmin * W_STRIDE + l];
      const int n = n0 + p0 + p;
      out[(size_t)n * SD + s * DCW + l] = wq;
      float dq = zl[(p0 + p) * Z_STRIDE + l] - wq;
      float sqq = dq * dq;
      #pragma unroll
      for (int off = 1; off < 64; off <<= 1) sqq += __shfl_xor(sqq, off);
      if (l == 0) lq_acc += sqq;
    }

    // ========= Phase B: u[p][d] = sum_k r[p][k] * w[k][d] =========
    // lane tile: d = 4*d4b..4*d4b+3, p in {psub, psub+4}
    float4 u0 = make_float4(0.f, 0.f, 0.f, 0.f);
    float4 u1 = make_float4(0.f, 0.f, 0.f, 0.f);
    const float* wB  = w68 + d4b * 4;
    const float* r0p = rtw + psub * R_STRIDE;
    const float* r1p = rtw + (psub + 4) * R_STRIDE;
    #pragma unroll 2
    for (int k0 = 0; k0 < KCW; k0 += 4) {
      const float4 r0 = *(const float4*)(r0p + k0);
      const float4 r1 = *(const float4*)(r1p + k0);
      #pragma unroll
      for (int j = 0; j < 4; ++j) {
        const float4 wv = *(const float4*)(wB + (k0 + j) * W_STRIDE);
        const float rj0 = (j == 0) ? r0.x : (j == 1) ? r0.y : (j == 2) ? r0.z : r0.w;
        const float rj1 = (j == 0) ? r1.x : (j == 1) ? r1.y : (j == 2) ? r1.z : r1.w;
        u0.x = fmaf(rj0, wv.x, u0.x);
        u0.y = fmaf(rj0, wv.y, u0.y);
        u0.z = fmaf(rj0, wv.z, u0.z);
        u0.w = fmaf(rj0, wv.w, u0.w);
        u1.x = fmaf(rj1, wv.x, u1.x);
        u1.y = fmaf(rj1, wv.y, u1.y);
        u1.z = fmaf(rj1, wv.z, u1.z);
        u1.w = fmaf(rj1, wv.w, u1.w);
      }
    }
    // loss_w partials: sum_d (u/R - w_qmin)^2
    {
      const float invR0 = 1.0f / Rme0;
      const float invR1 = 1.0f / Rme1;
      const float4 zq0 = *(const float4*)(w68 + kq0 * W_STRIDE + d4b * 4);
      const float4 zq1 = *(const float4*)(w68 + kq1 * W_STRIDE + d4b * 4);
      float ax = fmaf(u0.x, invR0, -zq0.x);
      float ay = fmaf(u0.y, invR0, -zq0.y);
      float az = fmaf(u0.z, invR0, -zq0.z);
      float aw = fmaf(u0.w, invR0, -zq0.w);
      float v0 = ax*ax + ay*ay + az*az + aw*aw;
      float bx = fmaf(u1.x, invR1, -zq1.x);
      float by = fmaf(u1.y, invR1, -zq1.y);
      float bz = fmaf(u1.z, invR1, -zq1.z);
      float bw = fmaf(u1.w, invR1, -zq1.w);
      float v1 = bx*bx + by*by + bz*bz + bw*bw;
      #pragma unroll
      for (int off = 4; off < 64; off <<= 1) {   // reduce over d4 within psub class
        v0 += __shfl_xor(v0, off);
        v1 += __shfl_xor(v1, off);
      }
      if (d4b == 0) lw_acc += v0 + v1;
    }
  }

  // ---- block loss reduction -> atomicAdd ----
  float total = lq_acc + lw_acc;
  #pragma unroll
  for (int off = 1; off < 64; off <<= 1) total += __shfl_xor(total, off);
  if (l == 0) red[wave] = total;
  __syncthreads();
  if (t == 0) {
    float sum = red[0] + red[1] + red[2] + red[3];
    atomicAdd(loss_out, sum * (1.0f / 16777216.0f));
  }
}

extern "C" void kernel_launch(void* const* d_in, const int* in_sizes, int n_in,
                              void* d_out, int out_size, void* d_ws, size_t ws_size,
                              hipStream_t stream) {
  const float* z = (const float*)d_in[0];
  const float* w = (const float*)d_in[1];
  float* out  = (float*)d_out;
  float* loss = out + (size_t)NPTS * SD;

  (void)hipFuncSetAttribute(reinterpret_cast<const void*>(pq_main),
                            hipFuncAttributeMaxDynamicSharedMemorySize, LDS_BYTES);

  pq_zero_loss<<<1, 1, 0, stream>>>(loss);
  pq_main<<<dim3((NPTS / PT) * SNS), dim3(256), LDS_BYTES, stream>>>(z, w, out, loss);
}

// Round 4
// 465.106 us; speedup vs baseline: 1.4712x; 1.4712x over previous
//
#include <hip/hip_runtime.h>
#include <math.h>

// PQ train-mode forward, MI355X fp32 VALU kernel, v2.
// z: [8,4096,512] fp32 -> N=32768 points, S=8 subspaces, D=64
// weight: [S=8][K=256][D=64] fp32
// out: z_q (16777216 fp32) ++ loss (1 fp32)
//
// v2: 512-thr blocks (8 waves, 2/SIMD), PT=64; Phase B all-8-points-per-lane
// with broadcast r reads (bank-skewed) + k-quartered replicas; loss_q butterfly
// removed; argmin/rsum butterflies interleaved across points.

#define SNS   8
#define KCW   256
#define DCW   64
#define NPTS  32768
#define SD    512
#define PT    64           // points per block (8 per wave)
#define EPS2F 1e-10f

#define W_STRIDE 68        // 272B rows: 16B aligned, 8-round (optimal) wave reads
#define Z_STRIDE 68
#define R_STRIDE 264       // 1056B rows: 16B aligned

#define W_OFF   0
#define W_FL    (KCW * W_STRIDE)            // 17408
#define Z_OFF   (W_OFF + W_FL)              // 17408
#define Z_FL    (PT * Z_STRIDE)             // 4352
#define R_OFF   (Z_OFF + Z_FL)              // 21760
#define R_FL    (8 * 8 * R_STRIDE)          // 16896
#define C2_OFF  (R_OFF + R_FL)              // 38656
#define X2_OFF  (C2_OFF + KCW)              // 38912
#define RED_OFF (X2_OFF + PT)               // 38976
#define LDS_FL  (RED_OFF + 8)               // 38984
#define LDS_BYTES (LDS_FL * 4)              // 155936 B < 160 KiB

__global__ void pq_zero_loss(float* loss) { *loss = 0.0f; }

__global__ __launch_bounds__(512, 2)
void pq_main(const float* __restrict__ z, const float* __restrict__ w,
             float* __restrict__ out, float* __restrict__ loss_out) {
  extern __shared__ float lds[];
  float* w68 = lds + W_OFF;
  float* zl  = lds + Z_OFF;
  float* rt  = lds + R_OFF;
  float* c2l = lds + C2_OFF;
  float* x2l = lds + X2_OFF;
  float* red = lds + RED_OFF;

  const int t    = threadIdx.x;
  const int s    = blockIdx.x >> 9;       // 512 tiles per s, contiguous: w L2-hot
  const int tile = blockIdx.x & 511;
  const int n0   = tile * PT;

  // ---- stage weight[s] -> w68 [K][68] (coalesced float4) ----
  {
    const float* ws = w + (size_t)s * (KCW * DCW);
    #pragma unroll
    for (int pass = 0; pass < 8; ++pass) {
      int idx = pass * 512 + t;           // float4 index in [0,4096)
      int k  = idx >> 4;
      int d4 = idx & 15;
      float4 v = *(const float4*)(ws + idx * 4);
      *(float4*)(w68 + k * W_STRIDE + d4 * 4) = v;
    }
  }
  // ---- stage z tile -> zl [PT][68]; x2 via 16-lane shuffle ----
  {
    #pragma unroll
    for (int pass = 0; pass < 2; ++pass) {
      int idx = pass * 512 + t;           // [0,1024)
      int i  = idx >> 4;
      int d4 = idx & 15;
      float4 v = *(const float4*)(z + (size_t)(n0 + i) * SD + s * DCW + d4 * 4);
      *(float4*)(zl + i * Z_STRIDE + d4 * 4) = v;
      float sq = v.x*v.x + v.y*v.y + v.z*v.z + v.w*v.w;
      sq += __shfl_xor(sq, 1);
      sq += __shfl_xor(sq, 2);
      sq += __shfl_xor(sq, 4);
      sq += __shfl_xor(sq, 8);
      if (d4 == 0) x2l[i] = sq;
    }
  }
  __syncthreads();
  // ---- c2[k] = ||w_k||^2 ----
  if (t < KCW) {
    float acc = 0.f;
    const float* row = w68 + t * W_STRIDE;
    #pragma unroll
    for (int d4 = 0; d4 < 16; ++d4) {
      float4 v = *(const float4*)(row + d4 * 4);
      acc += v.x*v.x + v.y*v.y + v.z*v.z + v.w*v.w;
    }
    c2l[t] = acc;
  }
  __syncthreads();

  const int wave = t >> 6;
  const int l    = t & 63;
  const int p0   = wave * 8;
  float* rtw = rt + wave * (8 * R_STRIDE);

  float c2r[4];
  #pragma unroll
  for (int g = 0; g < 4; ++g) c2r[g] = c2l[l + 64 * g];

  // ================= Phase A: xc[p][k]  (k = l + 64g) =================
  float acc[8][4];
  #pragma unroll
  for (int p = 0; p < 8; ++p)
    #pragma unroll
    for (int g = 0; g < 4; ++g) acc[p][g] = 0.f;

  {
    const float* wbase = w68 + l * W_STRIDE;
    #pragma unroll 4
    for (int d4 = 0; d4 < 16; ++d4) {
      float4 wv[4];
      #pragma unroll
      for (int g = 0; g < 4; ++g)
        wv[g] = *(const float4*)(wbase + g * (64 * W_STRIDE) + d4 * 4);
      #pragma unroll
      for (int p = 0; p < 8; ++p) {
        const float4 zv = *(const float4*)(zl + (p0 + p) * Z_STRIDE + d4 * 4);
        #pragma unroll
        for (int g = 0; g < 4; ++g) {
          acc[p][g] = fmaf(zv.x, wv[g].x, acc[p][g]);
          acc[p][g] = fmaf(zv.y, wv[g].y, acc[p][g]);
          acc[p][g] = fmaf(zv.z, wv[g].z, acc[p][g]);
          acc[p][g] = fmaf(zv.w, wv[g].w, acc[p][g]);
        }
      }
    }
  }

  // ======== Phase A epilogue: d2, r->LDS, interleaved argmin/rsum ========
  float dmin[8]; int kmin[8]; float rsum[8];
  #pragma unroll
  for (int p = 0; p < 8; ++p) {
    const float x2 = x2l[p0 + p];
    float d2g[4];
    #pragma unroll
    for (int g = 0; g < 4; ++g) {
      float m = fmaf(-2.f, acc[p][g], x2 + c2r[g]);
      d2g[g] = fmaxf(m, 0.f);
    }
    float dm = d2g[0];
    int   km = l;
    float rs = 0.f;
    #pragma unroll
    for (int g = 0; g < 4; ++g) {
      float r = rsqrtf(fmaxf(d2g[g], EPS2F));   // 1/max(dist,EPS)
      rs += r;
      rtw[p * R_STRIDE + l + 64 * g] = r;
      if (g > 0 && d2g[g] < dm) { dm = d2g[g]; km = l + 64 * g; }
    }
    dmin[p] = dm; kmin[p] = km; rsum[p] = rs;
  }
  // interleaved 6-stage butterflies (8 points in flight)
  #pragma unroll
  for (int off = 1; off < 64; off <<= 1) {
    #pragma unroll
    for (int p = 0; p < 8; ++p) {
      float od = __shfl_xor(dmin[p], off);
      int   ok = __shfl_xor(kmin[p], off);
      float oR = __shfl_xor(rsum[p], off);
      if (od < dmin[p] || (od == dmin[p] && ok < kmin[p])) { dmin[p] = od; kmin[p] = ok; }
      rsum[p] += oR;
    }
  }

  // ---- z_q write + per-lane loss_q accumulation (no butterfly) ----
  float lq_lane = 0.f;
  #pragma unroll
  for (int p = 0; p < 8; ++p) {
    const float wq = w68[kmin[p] * W_STRIDE + l];
    const int n = n0 + p0 + p;
    out[(size_t)n * SD + s * DCW + l] = wq;
    float dq = zl[(p0 + p) * Z_STRIDE + l] - wq;
    lq_lane = fmaf(dq, dq, lq_lane);
  }
  __syncthreads();   // rtw visible wave-locally already, but cheap; keeps waves roughly phased

  // ========= Phase B: u[p][d] = sum_k r[p][k] * w[k][d] =========
  // lane = (d4b 0..15, kk 0..3); lane computes all 8 p x 4 d over k in
  // [64kk, 64kk+64); bank-skewed step order se=(step+2kk)&15 -> conflict-free.
  const int d4b = l & 15;
  const int kk  = l >> 4;
  float u[8][4];
  #pragma unroll
  for (int p = 0; p < 8; ++p)
    #pragma unroll
    for (int c = 0; c < 4; ++c) u[p][c] = 0.f;

  {
    const float* wB = w68 + d4b * 4;
    #pragma unroll 2
    for (int step = 0; step < 16; ++step) {
      const int se = (step + 2 * kk) & 15;
      const int k0 = kk * 64 + 4 * se;
      float4 r4[8];
      #pragma unroll
      for (int p = 0; p < 8; ++p)
        r4[p] = *(const float4*)(rtw + p * R_STRIDE + k0);
      #pragma unroll
      for (int j = 0; j < 4; ++j) {
        const float4 wv = *(const float4*)(wB + (k0 + j) * W_STRIDE);
        #pragma unroll
        for (int p = 0; p < 8; ++p) {
          const float rj = (j == 0) ? r4[p].x : (j == 1) ? r4[p].y
                         : (j == 2) ? r4[p].z : r4[p].w;
          u[p][0] = fmaf(rj, wv.x, u[p][0]);
          u[p][1] = fmaf(rj, wv.y, u[p][1]);
          u[p][2] = fmaf(rj, wv.z, u[p][2]);
          u[p][3] = fmaf(rj, wv.w, u[p][3]);
        }
      }
    }
  }
  // cross-replica (kk) reduction: xor 16, 32
  #pragma unroll
  for (int p = 0; p < 8; ++p)
    #pragma unroll
    for (int c = 0; c < 4; ++c) {
      float v = u[p][c];
      v += __shfl_xor(v, 16);
      v += __shfl_xor(v, 32);
      u[p][c] = v;
    }

  // ---- loss_w partials: sum_d (u/R - w_qmin)^2  (x4 replicated -> *0.25) ----
  float lw_lane = 0.f;
  #pragma unroll
  for (int p = 0; p < 8; ++p) {
    const float invR = 1.0f / rsum[p];
    const float4 zq = *(const float4*)(w68 + kmin[p] * W_STRIDE + d4b * 4);
    float ex = fmaf(u[p][0], invR, -zq.x);
    float ey = fmaf(u[p][1], invR, -zq.y);
    float ez = fmaf(u[p][2], invR, -zq.z);
    float ew = fmaf(u[p][3], invR, -zq.w);
    lw_lane += ex*ex + ey*ey + ez*ez + ew*ew;
  }

  // ---- block loss reduction -> atomicAdd ----
  float total = lq_lane + 0.25f * lw_lane;
  #pragma unroll
  for (int off = 1; off < 64; off <<= 1) total += __shfl_xor(total, off);
  if (l == 0) red[wave] = total;
  __syncthreads();
  if (t == 0) {
    float sum = 0.f;
    #pragma unroll
    for (int wv = 0; wv < 8; ++wv) sum += red[wv];
    atomicAdd(loss_out, sum * (1.0f / 16777216.0f));
  }
}

extern "C" void kernel_launch(void* const* d_in, const int* in_sizes, int n_in,
                              void* d_out, int out_size, void* d_ws, size_t ws_size,
                              hipStream_t stream) {
  const float* z = (const float*)d_in[0];
  const float* w = (const float*)d_in[1];
  float* out  = (float*)d_out;
  float* loss = out + (size_t)NPTS * SD;

  (void)hipFuncSetAttribute(reinterpret_cast<const void*>(pq_main),
                            hipFuncAttributeMaxDynamicSharedMemorySize, LDS_BYTES);

  pq_zero_loss<<<1, 1, 0, stream>>>(loss);
  pq_main<<<dim3((NPTS / PT) * SNS), dim3(512), LDS_BYTES, stream>>>(z, w, out, loss);
}

// Round 6
// 378.943 us; speedup vs baseline: 1.8057x; 1.2274x over previous
//
#include <hip/hip_runtime.h>
#include <math.h>

// PQ train-mode forward, MI355X, v3b: exact-split bf16 MFMA.
// z: [8,4096,512] fp32 (N=32768 pts, S=8, D=64); weight: [8][256][64] fp32
// out: z_q (16777216 fp32, bit-exact codeword gather) ++ loss (1 fp32)
//
// v3b fix: w staging + wT restage loops cover all 4096 float4 (pass<8, was
// pass<4 -> codewords 128..255 were uninitialized LDS garbage -> NaN).
//
// fp32 x == bf16(h)+bf16(m)+bf16(l) exactly. Phase A (xc = Z.W^T) uses
// 6-term split (hh,hm,mh,hl,lh,mm) -> d2 err ~1e-5. Phase B (z_w = R.W)
// uses r_h.(w_h+w_m) -> loss err ~2e-3 << 8.9e-2 threshold.
// loss_q = sum_p d2min (gram identity). 512 thr = 8 waves, 1 block/CU.

typedef __attribute__((ext_vector_type(8))) short b16x8;
typedef __attribute__((ext_vector_type(4))) float f32x4;
typedef __attribute__((ext_vector_type(4))) int i32x4;
typedef __attribute__((ext_vector_type(4))) unsigned short u16x4;

#define SNS 8
#define KCW 256
#define DCW 64
#define NPTS 32768
#define SD 512
#define PT 64

// LDS byte offsets (peak 153600 B < 160 KiB -> 1 block/CU, 2 waves/SIMD)
#define WH    0        // [256][64] bf16 swz (32K): w_hi   | Phase B: wT_hi [64][256]
#define WM    32768    // w_mid                           | Phase B: wT_mid
#define WL    65536    // w_lo (dead after gather)
#define ZP0   98304    // z planes 3x[64][64] bf16 swz (24K) | overlay: r [64][256] (32K)
#define RPL   98304
#define C2O   131072   // c2[256] f32
#define X2O   132096   // x2[64] f32
#define PMINO 132352   // [64][4] f32
#define PKIDO 133376   // [64][4] i32
#define PRSUMO 134400  // [64][4] f32
#define INVRO 135424   // [64] f32
#define KMINO 135680   // [64] i32
#define REDO  135936   // [8] f32
#define ZQFO  136192   // [64][68] f32 (17408 B)
#define LDS_BYTES 153600

__device__ __forceinline__ unsigned short f2bf(float x) {
  unsigned u = __float_as_uint(x);
  return (unsigned short)((u + 0x7FFFu + ((u >> 16) & 1u)) >> 16);
}
__device__ __forceinline__ float bf2f(unsigned short b) {
  return __uint_as_float(((unsigned)b) << 16);
}

__global__ void pq_zero_loss(float* loss) { *loss = 0.0f; }

__global__ __launch_bounds__(512, 2)
void pq_main(const float* __restrict__ z, const float* __restrict__ w,
             float* __restrict__ out, float* __restrict__ loss_out) {
  extern __shared__ char lds[];
  const int t  = threadIdx.x;
  const int s  = blockIdx.x >> 9;
  const int n0 = (blockIdx.x & 511) * PT;
  const int wv = t >> 6;
  const int l  = t & 63;
  const int g  = l >> 4;     // 0..3
  const int fr = l & 15;     // 0..15

  float* c2l = (float*)(lds + C2O);
  float* x2l = (float*)(lds + X2O);

  // ============ stage: w -> 3 bf16 planes (swz), c2; z -> 3 planes, x2 ============
  {
    const float* ws = w + (size_t)s * (KCW * DCW);
    #pragma unroll
    for (int pass = 0; pass < 8; ++pass) {           // 8*512 = 4096 float4 = 256x64
      int fidx = pass * 512 + t;
      int k = fidx >> 4, d4 = fidx & 15;
      float4 v = *(const float4*)(ws + fidx * 4);
      u16x4 hq, mq, lq;
      float xs[4] = {v.x, v.y, v.z, v.w};
      #pragma unroll
      for (int j = 0; j < 4; ++j) {
        unsigned short h = f2bf(xs[j]); float hf = bf2f(h);
        unsigned short m = f2bf(xs[j] - hf); float mf = bf2f(m);
        unsigned short o = f2bf((xs[j] - hf) - mf);
        hq[j] = h; mq[j] = m; lq[j] = o;
      }
      int addr = k * 128 + (((d4 >> 1) ^ (k & 7)) << 4) + (d4 & 1) * 8;
      *(u16x4*)(lds + WH + addr) = hq;
      *(u16x4*)(lds + WM + addr) = mq;
      *(u16x4*)(lds + WL + addr) = lq;
      float sq = v.x*v.x + v.y*v.y + v.z*v.z + v.w*v.w;
      sq += __shfl_xor(sq, 1); sq += __shfl_xor(sq, 2);
      sq += __shfl_xor(sq, 4); sq += __shfl_xor(sq, 8);
      if (d4 == 0) c2l[k] = sq;
    }
    #pragma unroll
    for (int pass = 0; pass < 2; ++pass) {           // 1024 float4 = 64x64
      int idx = pass * 512 + t;
      int i = idx >> 4, d4 = idx & 15;
      float4 v = *(const float4*)(z + (size_t)(n0 + i) * SD + s * DCW + d4 * 4);
      u16x4 hq, mq, lq;
      float xs[4] = {v.x, v.y, v.z, v.w};
      #pragma unroll
      for (int j = 0; j < 4; ++j) {
        unsigned short h = f2bf(xs[j]); float hf = bf2f(h);
        unsigned short m = f2bf(xs[j] - hf); float mf = bf2f(m);
        unsigned short o = f2bf((xs[j] - hf) - mf);
        hq[j] = h; mq[j] = m; lq[j] = o;
      }
      int addr = i * 128 + (((d4 >> 1) ^ (i & 7)) << 4) + (d4 & 1) * 8;
      *(u16x4*)(lds + ZP0 + 0     + addr) = hq;
      *(u16x4*)(lds + ZP0 + 8192  + addr) = mq;
      *(u16x4*)(lds + ZP0 + 16384 + addr) = lq;
      float sq = v.x*v.x + v.y*v.y + v.z*v.z + v.w*v.w;
      sq += __shfl_xor(sq, 1); sq += __shfl_xor(sq, 2);
      sq += __shfl_xor(sq, 4); sq += __shfl_xor(sq, 8);
      if (d4 == 0) x2l[i] = sq;
    }
  }
  __syncthreads();

  // ============ Phase A MFMA: xc[64 p][256 k], 6-term split ============
  const int mb = wv >> 2;   // 0..1 : points mb*32..+31
  const int nb = wv & 3;    // 0..3 : k nb*64..+63
  b16x8 za[3][2][2];        // [plane][mt2][kstep]
  #pragma unroll
  for (int pl = 0; pl < 3; ++pl)
    #pragma unroll
    for (int mt2 = 0; mt2 < 2; ++mt2)
      #pragma unroll
      for (int ks = 0; ks < 2; ++ks) {
        int row = mb * 32 + mt2 * 16 + fr;
        int addr = ZP0 + pl * 8192 + row * 128 + ((((4*ks + g) ^ (row & 7))) << 4);
        za[pl][mt2][ks] = *(const b16x8*)(lds + addr);
      }
  f32x4 acc[2][4];
  #pragma unroll
  for (int m2 = 0; m2 < 2; ++m2)
    #pragma unroll
    for (int nt = 0; nt < 4; ++nt)
      #pragma unroll
      for (int c = 0; c < 4; ++c) acc[m2][nt][c] = 0.f;

  #pragma unroll
  for (int ntp = 0; ntp < 2; ++ntp) {
    #pragma unroll
    for (int ks = 0; ks < 2; ++ks) {
      b16x8 bh[2], bm[2], bl[2];
      #pragma unroll
      for (int e = 0; e < 2; ++e) {
        int krow = nb * 64 + (2*ntp + e) * 16 + fr;
        int ab = krow * 128 + ((((4*ks + g) ^ (krow & 7))) << 4);
        bh[e] = *(const b16x8*)(lds + WH + ab);
        bm[e] = *(const b16x8*)(lds + WM + ab);
        bl[e] = *(const b16x8*)(lds + WL + ab);
      }
      #pragma unroll
      for (int e = 0; e < 2; ++e)
        #pragma unroll
        for (int m2 = 0; m2 < 2; ++m2) {
          int nt = 2*ntp + e;
          f32x4 a = acc[m2][nt];
          a = __builtin_amdgcn_mfma_f32_16x16x32_bf16(za[0][m2][ks], bh[e], a, 0, 0, 0);
          a = __builtin_amdgcn_mfma_f32_16x16x32_bf16(za[0][m2][ks], bm[e], a, 0, 0, 0);
          a = __builtin_amdgcn_mfma_f32_16x16x32_bf16(za[1][m2][ks], bh[e], a, 0, 0, 0);
          a = __builtin_amdgcn_mfma_f32_16x16x32_bf16(za[0][m2][ks], bl[e], a, 0, 0, 0);
          a = __builtin_amdgcn_mfma_f32_16x16x32_bf16(za[2][m2][ks], bh[e], a, 0, 0, 0);
          a = __builtin_amdgcn_mfma_f32_16x16x32_bf16(za[1][m2][ks], bm[e], a, 0, 0, 0);
          acc[m2][nt] = a;
        }
    }
  }
  __syncthreads();   // all waves past their za loads (r overlays z planes)

  // ============ Phase A epilogue: d2, r -> LDS (bf16), wave partials ============
  {
    float c2k[4];
    #pragma unroll
    for (int nt = 0; nt < 4; ++nt) c2k[nt] = c2l[nb * 64 + nt * 16 + fr];
    float dm[8]; int km[8]; float rs[8];
    #pragma unroll
    for (int m2 = 0; m2 < 2; ++m2)
      #pragma unroll
      for (int i = 0; i < 4; ++i) {
        int p = mb * 32 + m2 * 16 + g * 4 + i;
        float x2p = x2l[p];
        float bd = 3.4e38f; int bk = 0; float rsum = 0.f;
        #pragma unroll
        for (int nt = 0; nt < 4; ++nt) {
          int k = nb * 64 + nt * 16 + fr;
          float d2 = fmaxf(fmaf(-2.f, acc[m2][nt][i], x2p + c2k[nt]), 0.f);
          float rv = rsqrtf(fmaxf(d2, 1e-10f));
          rsum += rv;
          int slot = (k >> 3) ^ (p & 7);
          *(unsigned short*)(lds + RPL + p * 512 + (slot << 4) + (k & 7) * 2) = f2bf(rv);
          if (d2 < bd) { bd = d2; bk = k; }
        }
        int q = m2 * 4 + i;
        dm[q] = bd; km[q] = bk; rs[q] = rsum;
      }
    #pragma unroll
    for (int off = 1; off < 16; off <<= 1) {
      #pragma unroll
      for (int q = 0; q < 8; ++q) {
        float od = __shfl_xor(dm[q], off);
        int   ok = __shfl_xor(km[q], off);
        float orr = __shfl_xor(rs[q], off);
        if (od < dm[q] || (od == dm[q] && ok < km[q])) { dm[q] = od; km[q] = ok; }
        rs[q] += orr;
      }
    }
    if (fr == 0) {
      #pragma unroll
      for (int q = 0; q < 8; ++q) {
        int p = mb * 32 + (q >> 2) * 16 + g * 4 + (q & 3);
        ((float*)(lds + PMINO))[p * 4 + nb] = dm[q];
        ((int*)  (lds + PKIDO))[p * 4 + nb] = km[q];
        ((float*)(lds + PRSUMO))[p * 4 + nb] = rs[q];
      }
    }
  }
  __syncthreads();

  // ============ finalize (t<64): kmin, invR, loss_q partial ============
  float lq_acc = 0.f;
  if (t < 64) {
    f32x4 pm = *(const f32x4*)(lds + PMINO + t * 16);
    i32x4 pk = *(const i32x4*)(lds + PKIDO + t * 16);
    f32x4 pr = *(const f32x4*)(lds + PRSUMO + t * 16);
    float bd = pm[0]; int bk = pk[0];
    #pragma unroll
    for (int j = 1; j < 4; ++j) {
      if (pm[j] < bd || (pm[j] == bd && pk[j] < bk)) { bd = pm[j]; bk = pk[j]; }
    }
    float rsum = (pr[0] + pr[1]) + (pr[2] + pr[3]);
    ((int*)(lds + KMINO))[t] = bk;
    ((float*)(lds + INVRO))[t] = 1.0f / rsum;
    lq_acc = bd;
  }
  __syncthreads();

  // ============ gather: z_q = w[kmin] (exact h+m+l), global + zqf ============
  {
    int p = t >> 3, d8 = t & 7;
    int kmn = ((const int*)(lds + KMINO))[p];
    int base = kmn * 128 + ((d8 ^ (kmn & 7)) << 4);
    b16x8 hv = *(const b16x8*)(lds + WH + base);
    b16x8 mv = *(const b16x8*)(lds + WM + base);
    b16x8 lv = *(const b16x8*)(lds + WL + base);
    f32x4 o0, o1;
    #pragma unroll
    for (int j = 0; j < 4; ++j) {
      o0[j] = bf2f((unsigned short)hv[j]) + (bf2f((unsigned short)mv[j]) + bf2f((unsigned short)lv[j]));
      o1[j] = bf2f((unsigned short)hv[j+4]) + (bf2f((unsigned short)mv[j+4]) + bf2f((unsigned short)lv[j+4]));
    }
    float* og = out + (size_t)(n0 + p) * SD + s * DCW + d8 * 8;
    *(f32x4*)(og) = o0; *(f32x4*)(og + 4) = o1;
    *(f32x4*)(lds + ZQFO + (p * 68 + d8 * 8) * 4) = o0;
    *(f32x4*)(lds + ZQFO + (p * 68 + d8 * 8) * 4 + 16) = o1;
  }
  __syncthreads();

  // ============ restage w transposed: wT_h/wT_m [64 d][256 k] bf16 swz ============
  {
    const float* ws = w + (size_t)s * (KCW * DCW);
    #pragma unroll
    for (int pass = 0; pass < 8; ++pass) {           // 8*512 = 4096 float4 (full w)
      int fidx = pass * 512 + t;
      int k = fidx >> 4, d4 = fidx & 15;
      float4 v = *(const float4*)(ws + fidx * 4);
      float xs[4] = {v.x, v.y, v.z, v.w};
      #pragma unroll
      for (int j = 0; j < 4; ++j) {
        int d = d4 * 4 + j;
        unsigned short h = f2bf(xs[j]);
        unsigned short m = f2bf(xs[j] - bf2f(h));
        int addr = d * 512 + ((((k >> 3) ^ (d & 7))) << 4) + (k & 7) * 2;
        *(unsigned short*)(lds + WH + addr) = h;
        *(unsigned short*)(lds + WM + addr) = m;
      }
    }
  }
  __syncthreads();

  // ============ Phase B MFMA: z_w[64 p][64 d] = r . w  (r_h*(w_h+w_m)) ============
  const int mt  = wv >> 1;   // 0..3
  const int np2 = wv & 1;    // n-tiles {2np2, 2np2+1}
  f32x4 bacc[2];
  #pragma unroll
  for (int n2 = 0; n2 < 2; ++n2)
    #pragma unroll
    for (int c = 0; c < 4; ++c) bacc[n2][c] = 0.f;
  {
    int arow = mt * 16 + fr;
    #pragma unroll
    for (int ks = 0; ks < 8; ++ks) {
      int slot = ks * 4 + g;
      b16x8 ra = *(const b16x8*)(lds + RPL + arow * 512 + ((slot ^ (arow & 7)) << 4));
      #pragma unroll
      for (int n2 = 0; n2 < 2; ++n2) {
        int drow = (np2 * 2 + n2) * 16 + fr;
        int ab = drow * 512 + ((slot ^ (drow & 7)) << 4);
        b16x8 th = *(const b16x8*)(lds + WH + ab);
        b16x8 tm = *(const b16x8*)(lds + WM + ab);
        bacc[n2] = __builtin_amdgcn_mfma_f32_16x16x32_bf16(ra, th, bacc[n2], 0, 0, 0);
        bacc[n2] = __builtin_amdgcn_mfma_f32_16x16x32_bf16(ra, tm, bacc[n2], 0, 0, 0);
      }
    }
  }

  // ============ Phase B epilogue: loss_w = sum (z_w*invR - zq)^2 ============
  float lw_acc = 0.f;
  {
    float iv[4];
    #pragma unroll
    for (int i = 0; i < 4; ++i)
      iv[i] = ((const float*)(lds + INVRO))[mt * 16 + g * 4 + i];
    #pragma unroll
    for (int n2 = 0; n2 < 2; ++n2)
      #pragma unroll
      for (int i = 0; i < 4; ++i) {
        int p = mt * 16 + g * 4 + i;
        int d = (np2 * 2 + n2) * 16 + fr;
        float zq = ((const float*)(lds + ZQFO))[p * 68 + d];
        float e = fmaf(bacc[n2][i], iv[i], -zq);
        lw_acc = fmaf(e, e, lw_acc);
      }
  }

  // ============ loss reduce -> atomicAdd ============
  float total = lq_acc + lw_acc;
  #pragma unroll
  for (int off = 1; off < 64; off <<= 1) total += __shfl_xor(total, off);
  if (l == 0) ((float*)(lds + REDO))[wv] = total;
  __syncthreads();
  if (t == 0) {
    float sum = 0.f;
    #pragma unroll
    for (int i = 0; i < 8; ++i) sum += ((const float*)(lds + REDO))[i];
    atomicAdd(loss_out, sum * (1.0f / 16777216.0f));
  }
}

extern "C" void kernel_launch(void* const* d_in, const int* in_sizes, int n_in,
                              void* d_out, int out_size, void* d_ws, size_t ws_size,
                              hipStream_t stream) {
  const float* z = (const float*)d_in[0];
  const float* w = (const float*)d_in[1];
  float* out  = (float*)d_out;
  float* loss = out + (size_t)NPTS * SD;

  (void)hipFuncSetAttribute(reinterpret_cast<const void*>(pq_main),
                            hipFuncAttributeMaxDynamicSharedMemorySize, LDS_BYTES);

  pq_zero_loss<<<1, 1, 0, stream>>>(loss);
  pq_main<<<dim3((NPTS / PT) * SNS), dim3(512), LDS_BYTES, stream>>>(z, w, out, loss);
}